// Round 2
// baseline (627.414 us; speedup 1.0000x reference)
//
#include <hip/hip_runtime.h>

typedef __attribute__((ext_vector_type(8))) short bf8_t;   // 8 bf16 = 4 VGPRs
typedef __attribute__((ext_vector_type(4))) float f4_t;

#define MFMA16(a, b, c) __builtin_amdgcn_mfma_f32_16x16x32_bf16((a), (b), (c), 0, 0, 0)

// Swizzled weight store (bf16 element offsets). Fragment-major: for each
// (nblk,k) the 64 lanes' 16B chunks are contiguous -> 1KB coalesced loads.
#define OFF_FC1 0          // 64x128   chunks [0,1024)
#define OFF_FC2 8192       // 64x192   chunks [1024,2560)
#define OFF_FC3 20480      // 32x64    chunks [2560,2816)
#define OFF_AB1 22528      // 256x256  chunks [2816,11008)
#define OFF_AB2 88064      // 256x256  chunks [11008,19200)
#define W_CHUNKS 19200

#define ST 392             // LDS row stride (bf16): [0:128)=x|z_hx|z2, [128:384)=tanh(x)||tanh(m) -> h1
#define T_TILES 4

__device__ __forceinline__ unsigned short f2bf(float f) {
    unsigned int u = __builtin_bit_cast(unsigned int, f);
    u += 0x7FFFu + ((u >> 16) & 1u);
    return (unsigned short)(u >> 16);
}

__device__ __forceinline__ float fast_tanh(float x) {
    float e = __builtin_amdgcn_exp2f(x * 2.885390081777927f);
    return 1.0f - 2.0f * __builtin_amdgcn_rcpf(e + 1.0f);
}

// Convert fp32 weights -> bf16 in MFMA-fragment-major ("swizzled") order.
// chunk c holds 8 elems: nb,k,l15,quad with src row=nb*16+l15, col=k*32+quad*8.
__global__ void convert_weights_kernel(const float* __restrict__ fc1w, const float* __restrict__ fc2w,
                                       const float* __restrict__ fc3w, const float* __restrict__ ab1w,
                                       const float* __restrict__ ab2w, unsigned short* __restrict__ wc) {
    int c = blockIdx.x * 256 + threadIdx.x;
    if (c >= W_CHUNKS) return;
    const float* p;
#define SWZ(SRC, LC, K32C, KC)                                                  \
    {                                                                           \
        int lc = (LC);                                                          \
        int quad = lc & 3, l15 = (lc >> 2) & 15, t6 = lc >> 6;                  \
        int k = t6 % (K32C), nb = t6 / (K32C);                                  \
        p = (SRC) + (size_t)(nb * 16 + l15) * (KC) + k * 32 + quad * 8;         \
    }
    if (c < 1024)       SWZ(fc1w, c,          4, 128)
    else if (c < 2560)  SWZ(fc2w, c - 1024,   6, 192)
    else if (c < 2816)  SWZ(fc3w, c - 2560,   2, 64)
    else if (c < 11008) SWZ(ab1w, c - 2816,   8, 256)
    else                SWZ(ab2w, c - 11008,  8, 256)
#undef SWZ
    float4 v0 = *(const float4*)p;
    float4 v1 = *(const float4*)(p + 4);
    ushort4 o0, o1;
    o0.x = f2bf(v0.x); o0.y = f2bf(v0.y); o0.z = f2bf(v0.z); o0.w = f2bf(v0.w);
    o1.x = f2bf(v1.x); o1.y = f2bf(v1.y); o1.z = f2bf(v1.z); o1.w = f2bf(v1.w);
    *(ushort4*)(wc + (size_t)c * 8)     = o0;
    *(ushort4*)(wc + (size_t)c * 8 + 4) = o1;
}

__global__ __launch_bounds__(256, 2)
void actor_fused_kernel(const float* __restrict__ x, const float* __restrict__ m,
                        const float* __restrict__ fc1_b, const float* __restrict__ fc2_b,
                        const float* __restrict__ fc3_b,
                        const float* __restrict__ ab_b1, const float* __restrict__ ab_b2,
                        const float* __restrict__ ab_w3, const float* __restrict__ ab_b3,
                        const unsigned short* __restrict__ wc,
                        float* __restrict__ out, int Brows)
{
    __shared__ __align__(16) unsigned short smem[64 * ST];
    __shared__ __align__(16) float nrm[64][4];
    __shared__ float pw[4][64];

    const int t    = threadIdx.x;
    const int w    = t >> 6;
    const int lane = t & 63;
    const int l15  = lane & 15;
    const int quad = lane >> 4;
    const int loff = (l15 * 4 + quad) * 8;     // lane offset within a 512-elem fragment block

    // ---- hoisted message-branch fragments (persist across tiles) ----
    bf8_t F1[4], F2[6], F3[2];
    #pragma unroll
    for (int k = 0; k < 4; k++) F1[k] = *(const bf8_t*)(wc + OFF_FC1 + (w * 4 + k) * 512 + loff);
    #pragma unroll
    for (int k = 0; k < 6; k++) F2[k] = *(const bf8_t*)(wc + OFF_FC2 + (w * 6 + k) * 512 + loff);
    #pragma unroll
    for (int k = 0; k < 2; k++) F3[k] = *(const bf8_t*)(wc + OFF_FC3 + ((w & 1) * 2 + k) * 512 + loff);

    // ---- hoisted biases / final weights ----
    const float bfc1 = fc1_b[w * 16 + l15];
    const float bfc2 = fc2_b[w * 16 + l15];
    const float bfc3 = fc3_b[(w & 1) * 16 + l15];
    float b1v[4], b2v[4], w3v[4];
    #pragma unroll
    for (int nt = 0; nt < 4; nt++) {
        b1v[nt] = ab_b1[w * 64 + nt * 16 + l15];
        b2v[nt] = ab_b2[w * 64 + nt * 16 + l15];
        w3v[nt] = ab_w3[w * 64 + nt * 16 + l15];
    }
    const float b3 = ab_b3[0];

    for (int it = 0; it < T_TILES; ++it) {
        const int r0 = (blockIdx.x * T_TILES + it) * 64;

        // ---------- stage: x->bf16, tanh(x), tanh(m) ----------
        {
            const float* xp = x + (size_t)r0 * 128;
            const float* mp = m + (size_t)r0 * 128;
            #pragma unroll
            for (int i = 0; i < 8; i++) {
                int idx = t * 4 + i * 1024;
                int row = idx >> 7, col = idx & 127;
                float4 v = *(const float4*)(xp + idx);
                float4 g = *(const float4*)(mp + idx);
                ushort4 raw, tx, tm;
                raw.x = f2bf(v.x); raw.y = f2bf(v.y); raw.z = f2bf(v.z); raw.w = f2bf(v.w);
                tx.x = f2bf(fast_tanh(v.x)); tx.y = f2bf(fast_tanh(v.y));
                tx.z = f2bf(fast_tanh(v.z)); tx.w = f2bf(fast_tanh(v.w));
                tm.x = f2bf(fast_tanh(g.x)); tm.y = f2bf(fast_tanh(g.y));
                tm.z = f2bf(fast_tanh(g.z)); tm.w = f2bf(fast_tanh(g.w));
                *(ushort4*)&smem[row * ST + col]       = raw;
                *(ushort4*)&smem[row * ST + 128 + col] = tx;
                *(ushort4*)&smem[row * ST + 256 + col] = tm;
            }
        }
        __syncthreads();   // B1

        // ---------- fc1 (block-coop: wave owns cols w*16..w*16+16, all 64 rows) ----------
        f4_t hc[4] = {f4_t{0,0,0,0}, f4_t{0,0,0,0}, f4_t{0,0,0,0}, f4_t{0,0,0,0}};
        #pragma unroll
        for (int k = 0; k < 4; k++)
            #pragma unroll
            for (int ms = 0; ms < 4; ms++) {
                bf8_t a = *(const bf8_t*)&smem[(ms * 16 + l15) * ST + k * 32 + quad * 8];
                hc[ms] = MFMA16(a, F1[k], hc[ms]);
            }
        {
            float pq[4][4];
            #pragma unroll
            for (int ms = 0; ms < 4; ms++)
                #pragma unroll
                for (int r = 0; r < 4; r++) { hc[ms][r] += bfc1; pq[ms][r] = hc[ms][r] * hc[ms][r]; }
            #pragma unroll
            for (int off = 1; off < 16; off <<= 1)
                #pragma unroll
                for (int ms = 0; ms < 4; ms++)
                    #pragma unroll
                    for (int r = 0; r < 4; r++) pq[ms][r] += __shfl_xor(pq[ms][r], off, 64);
            if (l15 == 0)
                #pragma unroll
                for (int ms = 0; ms < 4; ms++)
                    #pragma unroll
                    for (int r = 0; r < 4; r++) nrm[ms * 16 + quad * 4 + r][w] = pq[ms][r];
        }
        __syncthreads();   // B2 (partials ready; x region dead -> z overlay safe)
        #pragma unroll
        for (int ms = 0; ms < 4; ms++)
            #pragma unroll
            for (int r = 0; r < 4; r++) {
                int row = ms * 16 + quad * 4 + r;
                f4_t nv = *(const f4_t*)nrm[row];
                float inv = rsqrtf(fmaxf(nv[0] + nv[1] + nv[2] + nv[3], 1e-24f));
                smem[row * ST + w * 16 + l15] = f2bf(fast_tanh(hc[ms][r] * inv));
            }
        __syncthreads();   // B3 (z_hx ready)

        // ---------- fc2 (K=192: z_hx cols[0:64) + tanh(m) cols[256:384)) ----------
        f4_t zc[4] = {f4_t{0,0,0,0}, f4_t{0,0,0,0}, f4_t{0,0,0,0}, f4_t{0,0,0,0}};
        #pragma unroll
        for (int k = 0; k < 6; k++) {
            const int acol = (k < 2) ? (k * 32 + quad * 8) : (192 + k * 32 + quad * 8);
            #pragma unroll
            for (int ms = 0; ms < 4; ms++) {
                bf8_t a = *(const bf8_t*)&smem[(ms * 16 + l15) * ST + acol];
                zc[ms] = MFMA16(a, F2[k], zc[ms]);
            }
        }
        #pragma unroll
        for (int ms = 0; ms < 4; ms++)
            #pragma unroll
            for (int r = 0; r < 4; r++)
                smem[(ms * 16 + quad * 4 + r) * ST + 64 + w * 16 + l15] = f2bf(fast_tanh(zc[ms][r] + bfc2));
        __syncthreads();   // B4 (z2 ready)

        // ---------- fc3 (waves 0,1 only; N=32) ----------
        f4_t mc[4] = {f4_t{0,0,0,0}, f4_t{0,0,0,0}, f4_t{0,0,0,0}, f4_t{0,0,0,0}};
        if (w < 2) {
            #pragma unroll
            for (int k = 0; k < 2; k++)
                #pragma unroll
                for (int ms = 0; ms < 4; ms++) {
                    bf8_t a = *(const bf8_t*)&smem[(ms * 16 + l15) * ST + 64 + k * 32 + quad * 8];
                    mc[ms] = MFMA16(a, F3[k], mc[ms]);
                }
            float pq[4][4];
            #pragma unroll
            for (int ms = 0; ms < 4; ms++)
                #pragma unroll
                for (int r = 0; r < 4; r++) { mc[ms][r] += bfc3; pq[ms][r] = mc[ms][r] * mc[ms][r]; }
            #pragma unroll
            for (int off = 1; off < 16; off <<= 1)
                #pragma unroll
                for (int ms = 0; ms < 4; ms++)
                    #pragma unroll
                    for (int r = 0; r < 4; r++) pq[ms][r] += __shfl_xor(pq[ms][r], off, 64);
            if (l15 == 0)
                #pragma unroll
                for (int ms = 0; ms < 4; ms++)
                    #pragma unroll
                    for (int r = 0; r < 4; r++) nrm[ms * 16 + quad * 4 + r][w] = pq[ms][r];
        }
        __syncthreads();   // B5
        if (w < 2) {
            #pragma unroll
            for (int ms = 0; ms < 4; ms++)
                #pragma unroll
                for (int r = 0; r < 4; r++) {
                    int row = ms * 16 + quad * 4 + r;
                    float inv = rsqrtf(fmaxf(nrm[row][0] + nrm[row][1], 1e-24f));
                    out[(size_t)(r0 + row) * 32 + w * 16 + l15] = mc[ms][r] * inv;
                }
        }

        // ---------- ab1: h1 = relu([tanh(x)||tanh(m)] @ w1^T + b1), streamed swizzled B ----------
        f4_t acc[4][4];
        #pragma unroll
        for (int ms = 0; ms < 4; ms++)
            #pragma unroll
            for (int nt = 0; nt < 4; nt++) acc[ms][nt] = f4_t{0, 0, 0, 0};
        {
            bf8_t bcur[4], bnxt[4];
            #pragma unroll
            for (int nt = 0; nt < 4; nt++)
                bcur[nt] = *(const bf8_t*)(wc + OFF_AB1 + (size_t)((w * 4 + nt) * 8) * 512 + loff);
            #pragma unroll
            for (int k = 0; k < 8; k++) {
                if (k < 7)
                    #pragma unroll
                    for (int nt = 0; nt < 4; nt++)
                        bnxt[nt] = *(const bf8_t*)(wc + OFF_AB1 + (size_t)((w * 4 + nt) * 8 + k + 1) * 512 + loff);
                bf8_t a4[4];
                #pragma unroll
                for (int ms = 0; ms < 4; ms++)
                    a4[ms] = *(const bf8_t*)&smem[(ms * 16 + l15) * ST + 128 + k * 32 + quad * 8];
                #pragma unroll
                for (int nt = 0; nt < 4; nt++)
                    #pragma unroll
                    for (int ms = 0; ms < 4; ms++) acc[ms][nt] = MFMA16(a4[ms], bcur[nt], acc[ms][nt]);
                if (k < 7)
                    #pragma unroll
                    for (int nt = 0; nt < 4; nt++) bcur[nt] = bnxt[nt];
            }
        }
        __syncthreads();   // B6 (all tanh-region reads done before h1 overwrite)
        #pragma unroll
        for (int ms = 0; ms < 4; ms++)
            #pragma unroll
            for (int nt = 0; nt < 4; nt++)
                #pragma unroll
                for (int r = 0; r < 4; r++)
                    smem[(ms * 16 + quad * 4 + r) * ST + 128 + w * 64 + nt * 16 + l15] =
                        f2bf(fmaxf(acc[ms][nt][r] + b1v[nt], 0.0f));
        __syncthreads();   // B7 (h1 ready)

        // ---------- ab2 + ab3 ----------
        #pragma unroll
        for (int ms = 0; ms < 4; ms++)
            #pragma unroll
            for (int nt = 0; nt < 4; nt++) acc[ms][nt] = f4_t{0, 0, 0, 0};
        {
            bf8_t bcur[4], bnxt[4];
            #pragma unroll
            for (int nt = 0; nt < 4; nt++)
                bcur[nt] = *(const bf8_t*)(wc + OFF_AB2 + (size_t)((w * 4 + nt) * 8) * 512 + loff);
            #pragma unroll
            for (int k = 0; k < 8; k++) {
                if (k < 7)
                    #pragma unroll
                    for (int nt = 0; nt < 4; nt++)
                        bnxt[nt] = *(const bf8_t*)(wc + OFF_AB2 + (size_t)((w * 4 + nt) * 8 + k + 1) * 512 + loff);
                bf8_t a4[4];
                #pragma unroll
                for (int ms = 0; ms < 4; ms++)
                    a4[ms] = *(const bf8_t*)&smem[(ms * 16 + l15) * ST + 128 + k * 32 + quad * 8];
                #pragma unroll
                for (int nt = 0; nt < 4; nt++)
                    #pragma unroll
                    for (int ms = 0; ms < 4; ms++) acc[ms][nt] = MFMA16(a4[ms], bcur[nt], acc[ms][nt]);
                if (k < 7)
                    #pragma unroll
                    for (int nt = 0; nt < 4; nt++) bcur[nt] = bnxt[nt];
            }
        }
        {
            float p[4][4];
            #pragma unroll
            for (int ms = 0; ms < 4; ms++)
                #pragma unroll
                for (int r = 0; r < 4; r++) {
                    float s = 0.0f;
                    #pragma unroll
                    for (int nt = 0; nt < 4; nt++) s += fmaxf(acc[ms][nt][r] + b2v[nt], 0.0f) * w3v[nt];
                    p[ms][r] = s;
                }
            #pragma unroll
            for (int off = 1; off < 16; off <<= 1)
                #pragma unroll
                for (int ms = 0; ms < 4; ms++)
                    #pragma unroll
                    for (int r = 0; r < 4; r++) p[ms][r] += __shfl_xor(p[ms][r], off, 64);
            if (l15 == 0)
                #pragma unroll
                for (int ms = 0; ms < 4; ms++)
                    #pragma unroll
                    for (int r = 0; r < 4; r++) pw[w][ms * 16 + quad * 4 + r] = p[ms][r];
        }
        __syncthreads();   // B8 (pw ready)
        if (t < 64)
            out[(size_t)Brows * 32 + r0 + t] = fast_tanh(pw[0][t] + pw[1][t] + pw[2][t] + pw[3][t] + b3);
    }
}

extern "C" void kernel_launch(void* const* d_in, const int* in_sizes, int n_in,
                              void* d_out, int out_size, void* d_ws, size_t ws_size,
                              hipStream_t stream) {
    const float* x     = (const float*)d_in[0];
    const float* m     = (const float*)d_in[1];
    const float* fc1_w = (const float*)d_in[2];
    const float* fc1_b = (const float*)d_in[3];
    const float* fc2_w = (const float*)d_in[4];
    const float* fc2_b = (const float*)d_in[5];
    const float* fc3_w = (const float*)d_in[6];
    const float* fc3_b = (const float*)d_in[7];
    const float* ab_w1 = (const float*)d_in[8];
    const float* ab_b1 = (const float*)d_in[9];
    const float* ab_w2 = (const float*)d_in[10];
    const float* ab_b2 = (const float*)d_in[11];
    const float* ab_w3 = (const float*)d_in[12];
    const float* ab_b3 = (const float*)d_in[13];
    float* out = (float*)d_out;
    unsigned short* wc = (unsigned short*)d_ws;
    int Brows = in_sizes[0] / 128;   // 262144

    convert_weights_kernel<<<(W_CHUNKS + 255) / 256, 256, 0, stream>>>(fc1_w, fc2_w, fc3_w, ab_w1, ab_w2, wc);
    actor_fused_kernel<<<Brows / (64 * T_TILES), 256, 0, stream>>>(x, m, fc1_b, fc2_b, fc3_b,
                                                                   ab_b1, ab_b2, ab_w3, ab_b3, wc, out, Brows);
}

// Round 3
// 473.752 us; speedup vs baseline: 1.3244x; 1.3244x over previous
//
#include <hip/hip_runtime.h>

typedef __attribute__((ext_vector_type(8))) short bf8_t;   // 8 bf16 = 4 VGPRs
typedef __attribute__((ext_vector_type(4))) float f4_t;

#define MFMA16(a, b, c) __builtin_amdgcn_mfma_f32_16x16x32_bf16((a), (b), (c), 0, 0, 0)

// Swizzled weight store (bf16 element offsets). Fragment-major: fragment block
// (nb,k) occupies 512 contiguous elems; lane (l15,quad) reads 16B at
// loff=(l15*4+quad)*8 -> one coalesced 1KB burst per wave B-load.
#define OFF_FC1 0          // 64x128   blocks [0,16)    t6 = nt*4+k
#define OFF_FC2 8192       // 64x192   blocks           t6 = nt*6+k
#define OFF_FC3 20480      // 32x64                     t6 = nt*2+k
#define OFF_AB1 22528      // 256x256                   t6 = nb*8+k
#define OFF_AB2 88064      // 256x256
#define W_CHUNKS 19200

// LDS row stride (bf16): [0:128)=x then z_hx[0:64)/z2[64:128), [128:384)=tanh(x)||tanh(m) then h1
#define ST 392

__device__ __forceinline__ unsigned short f2bf(float f) {
    unsigned int u = __builtin_bit_cast(unsigned int, f);
    u += 0x7FFFu + ((u >> 16) & 1u);               // round-to-nearest-even
    return (unsigned short)(u >> 16);
}

__device__ __forceinline__ float fast_tanh(float x) {
    float e = __builtin_amdgcn_exp2f(x * 2.885390081777927f);
    return 1.0f - 2.0f * __builtin_amdgcn_rcpf(e + 1.0f);
}

// fp32 weights -> bf16, fragment-major swizzle.
__global__ void convert_weights_kernel(const float* __restrict__ fc1w, const float* __restrict__ fc2w,
                                       const float* __restrict__ fc3w, const float* __restrict__ ab1w,
                                       const float* __restrict__ ab2w, unsigned short* __restrict__ wc) {
    int c = blockIdx.x * 256 + threadIdx.x;
    if (c >= W_CHUNKS) return;
    const float* p;
#define SWZ(SRC, LC, K32C, KC)                                                  \
    {                                                                           \
        int lc = (LC);                                                          \
        int quad = lc & 3, l15 = (lc >> 2) & 15, t6 = lc >> 6;                  \
        int k = t6 % (K32C), nb = t6 / (K32C);                                  \
        p = (SRC) + (size_t)(nb * 16 + l15) * (KC) + k * 32 + quad * 8;         \
    }
    if (c < 1024)       SWZ(fc1w, c,          4, 128)
    else if (c < 2560)  SWZ(fc2w, c - 1024,   6, 192)
    else if (c < 2816)  SWZ(fc3w, c - 2560,   2, 64)
    else if (c < 11008) SWZ(ab1w, c - 2816,   8, 256)
    else                SWZ(ab2w, c - 11008,  8, 256)
#undef SWZ
    float4 v0 = *(const float4*)p;
    float4 v1 = *(const float4*)(p + 4);
    ushort4 o0, o1;
    o0.x = f2bf(v0.x); o0.y = f2bf(v0.y); o0.z = f2bf(v0.z); o0.w = f2bf(v0.w);
    o1.x = f2bf(v1.x); o1.y = f2bf(v1.y); o1.z = f2bf(v1.z); o1.w = f2bf(v1.w);
    *(ushort4*)(wc + (size_t)c * 8)     = o0;
    *(ushort4*)(wc + (size_t)c * 8 + 4) = o1;
}

__global__ __launch_bounds__(256, 3)
void actor_fused_kernel(const float* __restrict__ x, const float* __restrict__ m,
                        const float* __restrict__ fc1_b, const float* __restrict__ fc2_b,
                        const float* __restrict__ fc3_b,
                        const float* __restrict__ ab_b1, const float* __restrict__ ab_b2,
                        const float* __restrict__ ab_w3, const float* __restrict__ ab_b3,
                        const unsigned short* __restrict__ wc,
                        float* __restrict__ out, int Brows)
{
    __shared__ __align__(16) unsigned short smem[64 * ST];
    __shared__ float pw[4][64];

    const int t    = threadIdx.x;
    const int wave = t >> 6;
    const int lane = t & 63;
    const int l15  = lane & 15;
    const int quad = lane >> 4;
    const int loff = (l15 * 4 + quad) * 8;     // lane offset within 512-elem fragment block
    const int r0   = blockIdx.x * 64;
    const int mrow = wave * 16;                // message branch: wave owns 16 rows

    // ---------------- stage: x -> bf16 + tanh(x); m -> tanh(m) ----------------
    {
        const float* xp = x + (size_t)r0 * 128;
        const float* mp = m + (size_t)r0 * 128;
        #pragma unroll
        for (int i = 0; i < 8; i++) {
            int idx = t * 4 + i * 1024;        // coalesced float4 over [0,8192)
            int row = idx >> 7, col = idx & 127;
            float4 v = *(const float4*)(xp + idx);
            float4 g = *(const float4*)(mp + idx);
            ushort4 raw, tx, tm;
            raw.x = f2bf(v.x); raw.y = f2bf(v.y); raw.z = f2bf(v.z); raw.w = f2bf(v.w);
            tx.x = f2bf(fast_tanh(v.x)); tx.y = f2bf(fast_tanh(v.y));
            tx.z = f2bf(fast_tanh(v.z)); tx.w = f2bf(fast_tanh(v.w));
            tm.x = f2bf(fast_tanh(g.x)); tm.y = f2bf(fast_tanh(g.y));
            tm.z = f2bf(fast_tanh(g.z)); tm.w = f2bf(fast_tanh(g.w));
            *(ushort4*)&smem[row * ST + col]       = raw;
            *(ushort4*)&smem[row * ST + 128 + col] = tx;
            *(ushort4*)&smem[row * ST + 256 + col] = tm;
        }
    }
    __syncthreads();

    // ---------------- fc1: hx = x @ fc1_w^T + b  (wave's own 16 rows, all 64 cols) ----------------
    f4_t hx[4] = {f4_t{0,0,0,0}, f4_t{0,0,0,0}, f4_t{0,0,0,0}, f4_t{0,0,0,0}};
    #pragma unroll
    for (int k = 0; k < 4; k++) {
        bf8_t a = *(const bf8_t*)&smem[(mrow + l15) * ST + k * 32 + quad * 8];
        #pragma unroll
        for (int nt = 0; nt < 4; nt++) {
            bf8_t b = *(const bf8_t*)(wc + OFF_FC1 + (nt * 4 + k) * 512 + loff);
            hx[nt] = MFMA16(a, b, hx[nt]);
        }
    }
    {
        float bia[4], ss[4] = {0, 0, 0, 0};
        #pragma unroll
        for (int nt = 0; nt < 4; nt++) bia[nt] = fc1_b[nt * 16 + l15];
        #pragma unroll
        for (int nt = 0; nt < 4; nt++)
            #pragma unroll
            for (int r = 0; r < 4; r++) { hx[nt][r] += bia[nt]; ss[r] += hx[nt][r] * hx[nt][r]; }
        #pragma unroll
        for (int off = 1; off < 16; off <<= 1)
            #pragma unroll
            for (int r = 0; r < 4; r++) ss[r] += __shfl_xor(ss[r], off, 64);
        float inv[4];
        #pragma unroll
        for (int r = 0; r < 4; r++) inv[r] = rsqrtf(fmaxf(ss[r], 1e-24f));
        // z_hx = tanh(l2norm(hx)) -> cols [0:64)
        #pragma unroll
        for (int nt = 0; nt < 4; nt++)
            #pragma unroll
            for (int r = 0; r < 4; r++)
                smem[(mrow + quad * 4 + r) * ST + nt * 16 + l15] = f2bf(fast_tanh(hx[nt][r] * inv[r]));
    }
    __syncthreads();

    // ---------------- fc2: z2 = tanh([z_hx||tanh(m)] @ fc2_w^T + b)  K=192 ----------------
    f4_t z2[4] = {f4_t{0,0,0,0}, f4_t{0,0,0,0}, f4_t{0,0,0,0}, f4_t{0,0,0,0}};
    #pragma unroll
    for (int k = 0; k < 6; k++) {
        int acol = (k < 2) ? (k * 32 + quad * 8) : (192 + k * 32 + quad * 8); // z_hx | tanh(m)
        bf8_t a = *(const bf8_t*)&smem[(mrow + l15) * ST + acol];
        #pragma unroll
        for (int nt = 0; nt < 4; nt++) {
            bf8_t b = *(const bf8_t*)(wc + OFF_FC2 + (nt * 6 + k) * 512 + loff);
            z2[nt] = MFMA16(a, b, z2[nt]);
        }
    }
    {
        float bia[4];
        #pragma unroll
        for (int nt = 0; nt < 4; nt++) bia[nt] = fc2_b[nt * 16 + l15];
        #pragma unroll
        for (int nt = 0; nt < 4; nt++)
            #pragma unroll
            for (int r = 0; r < 4; r++)
                smem[(mrow + quad * 4 + r) * ST + 64 + nt * 16 + l15] = f2bf(fast_tanh(z2[nt][r] + bia[nt]));
    }
    __syncthreads();

    // ---------------- fc3: msg = l2norm(z2 @ fc3_w^T + b)  K=64, N=32 ----------------
    {
        f4_t mg[2] = {f4_t{0,0,0,0}, f4_t{0,0,0,0}};
        #pragma unroll
        for (int k = 0; k < 2; k++) {
            bf8_t a = *(const bf8_t*)&smem[(mrow + l15) * ST + 64 + k * 32 + quad * 8];
            #pragma unroll
            for (int nt = 0; nt < 2; nt++) {
                bf8_t b = *(const bf8_t*)(wc + OFF_FC3 + (nt * 2 + k) * 512 + loff);
                mg[nt] = MFMA16(a, b, mg[nt]);
            }
        }
        float bia[2], ss[4] = {0, 0, 0, 0};
        #pragma unroll
        for (int nt = 0; nt < 2; nt++) bia[nt] = fc3_b[nt * 16 + l15];
        #pragma unroll
        for (int nt = 0; nt < 2; nt++)
            #pragma unroll
            for (int r = 0; r < 4; r++) { mg[nt][r] += bia[nt]; ss[r] += mg[nt][r] * mg[nt][r]; }
        #pragma unroll
        for (int off = 1; off < 16; off <<= 1)
            #pragma unroll
            for (int r = 0; r < 4; r++) ss[r] += __shfl_xor(ss[r], off, 64);
        float inv[4];
        #pragma unroll
        for (int r = 0; r < 4; r++) inv[r] = rsqrtf(fmaxf(ss[r], 1e-24f));
        #pragma unroll
        for (int nt = 0; nt < 2; nt++)
            #pragma unroll
            for (int r = 0; r < 4; r++)
                out[(size_t)(r0 + mrow + quad * 4 + r) * 32 + nt * 16 + l15] = mg[nt][r] * inv[r];
    }

    // ---------------- ab1: h1 = relu([tanh(x)||tanh(m)] @ w1^T + b1)  wave owns 64-col N-chunk ----------------
    f4_t acc[4][4];
    #pragma unroll
    for (int ms = 0; ms < 4; ms++)
        #pragma unroll
        for (int nt = 0; nt < 4; nt++) acc[ms][nt] = f4_t{0, 0, 0, 0};
    #pragma unroll
    for (int k = 0; k < 8; k++) {
        bf8_t a[4];
        #pragma unroll
        for (int ms = 0; ms < 4; ms++)
            a[ms] = *(const bf8_t*)&smem[(ms * 16 + l15) * ST + 128 + k * 32 + quad * 8];
        #pragma unroll
        for (int nt = 0; nt < 4; nt++) {
            bf8_t b = *(const bf8_t*)(wc + OFF_AB1 + ((wave * 4 + nt) * 8 + k) * 512 + loff);
            #pragma unroll
            for (int ms = 0; ms < 4; ms++) acc[ms][nt] = MFMA16(a[ms], b, acc[ms][nt]);
        }
    }
    {
        float bia[4];
        #pragma unroll
        for (int nt = 0; nt < 4; nt++) bia[nt] = ab_b1[wave * 64 + nt * 16 + l15];
        __syncthreads();   // all waves done reading tanh region before h1 overwrite
        #pragma unroll
        for (int ms = 0; ms < 4; ms++)
            #pragma unroll
            for (int nt = 0; nt < 4; nt++)
                #pragma unroll
                for (int r = 0; r < 4; r++)
                    smem[(ms * 16 + quad * 4 + r) * ST + 128 + wave * 64 + nt * 16 + l15] =
                        f2bf(fmaxf(acc[ms][nt][r] + bia[nt], 0.0f));
    }
    __syncthreads();

    // ---------------- ab2: h2 = relu(h1 @ w2^T + b2), fused ab3 dot ----------------
    f4_t acc2[4][4];
    #pragma unroll
    for (int ms = 0; ms < 4; ms++)
        #pragma unroll
        for (int nt = 0; nt < 4; nt++) acc2[ms][nt] = f4_t{0, 0, 0, 0};
    #pragma unroll
    for (int k = 0; k < 8; k++) {
        bf8_t a[4];
        #pragma unroll
        for (int ms = 0; ms < 4; ms++)
            a[ms] = *(const bf8_t*)&smem[(ms * 16 + l15) * ST + 128 + k * 32 + quad * 8];
        #pragma unroll
        for (int nt = 0; nt < 4; nt++) {
            bf8_t b = *(const bf8_t*)(wc + OFF_AB2 + ((wave * 4 + nt) * 8 + k) * 512 + loff);
            #pragma unroll
            for (int ms = 0; ms < 4; ms++) acc2[ms][nt] = MFMA16(a[ms], b, acc2[ms][nt]);
        }
    }
    {
        float bia[4], w3v[4];
        #pragma unroll
        for (int nt = 0; nt < 4; nt++) { bia[nt] = ab_b2[wave * 64 + nt * 16 + l15]; w3v[nt] = ab_w3[wave * 64 + nt * 16 + l15]; }
        float p[4][4];
        #pragma unroll
        for (int ms = 0; ms < 4; ms++)
            #pragma unroll
            for (int r = 0; r < 4; r++) {
                float s = 0.0f;
                #pragma unroll
                for (int nt = 0; nt < 4; nt++) s += fmaxf(acc2[ms][nt][r] + bia[nt], 0.0f) * w3v[nt];
                p[ms][r] = s;
            }
        #pragma unroll
        for (int off = 1; off < 16; off <<= 1)
            #pragma unroll
            for (int ms = 0; ms < 4; ms++)
                #pragma unroll
                for (int r = 0; r < 4; r++) p[ms][r] += __shfl_xor(p[ms][r], off, 64);
        if (l15 == 0) {
            #pragma unroll
            for (int ms = 0; ms < 4; ms++)
                #pragma unroll
                for (int r = 0; r < 4; r++) pw[wave][ms * 16 + quad * 4 + r] = p[ms][r];
        }
    }
    __syncthreads();
    if (t < 64) {
        float a = pw[0][t] + pw[1][t] + pw[2][t] + pw[3][t] + ab_b3[0];
        out[(size_t)Brows * 32 + r0 + t] = fast_tanh(a);   // MAX_ACTION = 1
    }
}

extern "C" void kernel_launch(void* const* d_in, const int* in_sizes, int n_in,
                              void* d_out, int out_size, void* d_ws, size_t ws_size,
                              hipStream_t stream) {
    const float* x     = (const float*)d_in[0];
    const float* m     = (const float*)d_in[1];
    const float* fc1_w = (const float*)d_in[2];
    const float* fc1_b = (const float*)d_in[3];
    const float* fc2_w = (const float*)d_in[4];
    const float* fc2_b = (const float*)d_in[5];
    const float* fc3_w = (const float*)d_in[6];
    const float* fc3_b = (const float*)d_in[7];
    const float* ab_w1 = (const float*)d_in[8];
    const float* ab_b1 = (const float*)d_in[9];
    const float* ab_w2 = (const float*)d_in[10];
    const float* ab_b2 = (const float*)d_in[11];
    const float* ab_w3 = (const float*)d_in[12];
    const float* ab_b3 = (const float*)d_in[13];
    float* out = (float*)d_out;
    unsigned short* wc = (unsigned short*)d_ws;
    int Brows = in_sizes[0] / 128;   // 262144

    convert_weights_kernel<<<(W_CHUNKS + 255) / 256, 256, 0, stream>>>(fc1_w, fc2_w, fc3_w, ab_w1, ab_w2, wc);
    actor_fused_kernel<<<Brows / 64, 256, 0, stream>>>(x, m, fc1_b, fc2_b, fc3_b,
                                                       ab_b1, ab_b2, ab_w3, ab_b3, wc, out, Brows);
}